// Round 1
// baseline (1202.832 us; speedup 1.0000x reference)
//
#include <hip/hip_runtime.h>

#define BT    2048
#define HDIM  1024
#define VDIM  32000
#define NSEQ  4
#define BETA  0.1f
#define IGNORE_IDX (-100)

#define BM 128
#define BN 128
#define BK 32
#define VSLICE 1280              // 25 slices exactly cover V=32000
#define NITER  (VSLICE / BN)     // 10
#define KTILES (HDIM / BK)       // 32
#define LDK    (BK + 8)          // 40 shorts = 80 B row stride: 16B-aligned b128, 2-way banks (free)

typedef __attribute__((ext_vector_type(8))) short bf16x8;
typedef __attribute__((ext_vector_type(8))) unsigned short u16x8;
typedef __attribute__((ext_vector_type(4))) float f32x4;

__device__ __forceinline__ unsigned short f2bf_rne(float f) {
  unsigned int u = __builtin_bit_cast(unsigned int, f);
  u += 0x7fffu + ((u >> 16) & 1u);   // round-to-nearest-even (no NaNs in this data)
  return (unsigned short)(u >> 16);
}

__device__ __forceinline__ void cvt_store8(unsigned short* dst, float4 a, float4 b) {
  u16x8 v;
  v[0] = f2bf_rne(a.x); v[1] = f2bf_rne(a.y); v[2] = f2bf_rne(a.z); v[3] = f2bf_rne(a.w);
  v[4] = f2bf_rne(b.x); v[5] = f2bf_rne(b.y); v[6] = f2bf_rne(b.z); v[7] = f2bf_rne(b.w);
  *(u16x8*)dst = v;
}

__global__ __launch_bounds__(256) void kto_zero_ws(float* p) {
  p[blockIdx.x * 256 + threadIdx.x] = 0.0f;
}

// Fused GEMM + online logsumexp partials.
// grid = (BT/BM, VDIM/VSLICE, 2 models); block = 256 (4 waves, 2x2 wave grid, 64x64/wave)
__global__ __launch_bounds__(256) void kto_lse_gemm(
    const float* __restrict__ Xp, const float* __restrict__ Wp, const float* __restrict__ Bp,
    const float* __restrict__ Xr, const float* __restrict__ Wr, const float* __restrict__ Br,
    const int* __restrict__ target, float* __restrict__ ws_se, float* __restrict__ ws_tg)
{
  const int model = blockIdx.z;
  const float* __restrict__ X  = model ? Xr : Xp;
  const float* __restrict__ W  = model ? Wr : Wp;
  const float* __restrict__ Bv = model ? Br : Bp;

  __shared__ unsigned short Asm[BM][LDK];   // 10 KB
  __shared__ unsigned short Bsm[BN][LDK];   // 10 KB

  const int tid  = threadIdx.x;
  const int wave = tid >> 6;
  const int lane = tid & 63;
  const int q    = lane >> 4;        // quad
  const int c    = lane & 15;        // col within MFMA tile (also m-index for A frag)
  const int mW   = (wave >> 1) * 64; // wave's row offset in block tile
  const int nW   = (wave & 1) * 64;  // wave's col offset in block tile
  const int mBase = blockIdx.x * BM;
  const int vBase = blockIdx.y * VSLICE;

  const int srow = tid >> 1;           // staging: 2 threads per row, 16 floats each
  const int scol = (tid & 1) << 4;

  // targets for this lane's 16 output rows (C/D layout: row = q*4 + r (+16*mi), col = c)
  int tgt_idx[4][4];
  #pragma unroll
  for (int mi = 0; mi < 4; ++mi)
    #pragma unroll
    for (int r = 0; r < 4; ++r)
      tgt_idx[mi][r] = target[mBase + mW + mi * 16 + q * 4 + r];

  float se_acc[4][4] = {};   // per-lane partial sum(exp(logit)) over this lane's columns
  float tg_acc[4][4] = {};   // target logit (hit at most once across all cols/slices)

  for (int it = 0; it < NITER; ++it) {
    const int nIterBase = vBase + it * BN;
    f32x4 acc[4][4] = {};

    for (int kt = 0; kt < KTILES; ++kt) {
      __syncthreads();   // protect previous iter's frag reads before overwrite
      {
        const float4* a4 = (const float4*)(X + (size_t)(mBase + srow) * HDIM + kt * BK + scol);
        float4 a0 = a4[0], a1 = a4[1], a2 = a4[2], a3 = a4[3];
        const float4* b4 = (const float4*)(W + (size_t)(nIterBase + srow) * HDIM + kt * BK + scol);
        float4 b0 = b4[0], b1 = b4[1], b2 = b4[2], b3 = b4[3];
        cvt_store8(&Asm[srow][scol],     a0, a1);
        cvt_store8(&Asm[srow][scol + 8], a2, a3);
        cvt_store8(&Bsm[srow][scol],     b0, b1);
        cvt_store8(&Bsm[srow][scol + 8], b2, b3);
      }
      __syncthreads();

      bf16x8 afr[4], bfr[4];
      #pragma unroll
      for (int mi = 0; mi < 4; ++mi)
        afr[mi] = *(const bf16x8*)&Asm[mW + mi * 16 + c][q * 8];
      #pragma unroll
      for (int ni = 0; ni < 4; ++ni)
        bfr[ni] = *(const bf16x8*)&Bsm[nW + ni * 16 + c][q * 8];
      #pragma unroll
      for (int mi = 0; mi < 4; ++mi)
        #pragma unroll
        for (int ni = 0; ni < 4; ++ni)
          acc[mi][ni] = __builtin_amdgcn_mfma_f32_16x16x32_bf16(afr[mi], bfr[ni], acc[mi][ni], 0, 0, 0);
    }

    // epilogue for this 128-wide vocab strip: bias + exp + target pick (registers only)
    #pragma unroll
    for (int ni = 0; ni < 4; ++ni) {
      const int col = nIterBase + nW + ni * 16 + c;
      const float bv = Bv[col];
      #pragma unroll
      for (int mi = 0; mi < 4; ++mi)
        #pragma unroll
        for (int r = 0; r < 4; ++r) {
          float logit = acc[mi][ni][r] + bv;
          se_acc[mi][r] += __expf(logit);
          if (tgt_idx[mi][r] == col) tg_acc[mi][r] += logit;
        }
    }
  }

  // reduce over the 16 columns held by the quad's 16 lanes, then one atomic per row
  #pragma unroll
  for (int mi = 0; mi < 4; ++mi)
    #pragma unroll
    for (int r = 0; r < 4; ++r) {
      float s = se_acc[mi][r];
      float t = tg_acc[mi][r];
      #pragma unroll
      for (int off = 1; off < 16; off <<= 1) {
        s += __shfl_xor(s, off, 64);
        t += __shfl_xor(t, off, 64);
      }
      if (c == 0) {
        const int row = mBase + mW + mi * 16 + q * 4 + r;
        atomicAdd(&ws_se[model * BT + row], s);
        atomicAdd(&ws_tg[model * BT + row], t);
      }
    }
}

__global__ __launch_bounds__(256) void kto_finalize(
    const float* __restrict__ ws_se, const float* __restrict__ ws_tg,
    const int* __restrict__ target, const int* __restrict__ pref,
    const float* __restrict__ kl, float* __restrict__ out)
{
  __shared__ float lr[NSEQ];
  const int tid = threadIdx.x;
  if (tid < NSEQ) lr[tid] = 0.0f;
  __syncthreads();
  for (int t = tid; t < BT; t += 256) {
    float d = 0.0f;
    if (target[t] != IGNORE_IDX) {
      float lp_p = ws_tg[t]      - __logf(ws_se[t]);
      float lp_r = ws_tg[BT + t] - __logf(ws_se[BT + t]);
      d = lp_p - lp_r;   // small per-token diff: no large-sum cancellation
    }
    atomicAdd(&lr[t >> 9], d);
  }
  __syncthreads();
  if (tid == 0) {
    float loss = 0.f, ch = 0.f, rj = 0.f;
    const float klv = kl[0];
    for (int b = 0; b < NSEQ; ++b) {
      float logratio = lr[b];
      bool p = pref[b] != 0;
      float mult = p ? 1.0f : -1.0f;
      float z = BETA * (logratio - klv) * mult;
      float sig = 1.0f / (1.0f + __expf(-z));
      loss += 1.0f - sig;
      float rw = BETA * logratio;
      if (p) ch += rw; else rj += rw;
    }
    out[0] = loss / (float)BT;
    out[1] = ch;
    out[2] = rj;
  }
}

extern "C" void kernel_launch(void* const* d_in, const int* in_sizes, int n_in,
                              void* d_out, int out_size, void* d_ws, size_t ws_size,
                              hipStream_t stream) {
  (void)in_sizes; (void)n_in; (void)out_size; (void)ws_size;
  const float* X    = (const float*)d_in[0];   // (2048, 1024)
  const float* W    = (const float*)d_in[1];   // (32000, 1024)
  const int*   tgt  = (const int*)d_in[2];     // (2048,)
  const float* bias = (const float*)d_in[3];   // (32000,)
  const int*   pref = (const int*)d_in[4];     // (4,)
  const float* Xr   = (const float*)d_in[5];
  const float* Wr   = (const float*)d_in[6];
  const float* br   = (const float*)d_in[7];
  const float* kl   = (const float*)d_in[8];
  float* out = (float*)d_out;

  float* ws_se = (float*)d_ws;        // [2][2048] sumexp partials
  float* ws_tg = ws_se + 2 * BT;      // [2][2048] target-logit partials

  kto_zero_ws<<<dim3((4 * BT) / 256), 256, 0, stream>>>(ws_se);

  dim3 grid(BT / BM, VDIM / VSLICE, 2);  // (16, 25, 2) = 800 blocks
  kto_lse_gemm<<<grid, 256, 0, stream>>>(X, W, bias, Xr, Wr, br, tgt, ws_se, ws_tg);

  kto_finalize<<<1, 256, 0, stream>>>(ws_se, ws_tg, tgt, pref, kl, out);
}

// Round 2
// 668.488 us; speedup vs baseline: 1.7993x; 1.7993x over previous
//
#include <hip/hip_runtime.h>

#define BT    2048
#define HDIM  1024
#define VDIM  32000
#define NSEQ  4
#define BETA  0.1f
#define IGNORE_IDX (-100)

typedef __attribute__((ext_vector_type(8))) short bf16x8;
typedef __attribute__((ext_vector_type(8))) unsigned short u16x8;
typedef __attribute__((ext_vector_type(4))) float f32x4;

// ---------------- ws layout ----------------
// floats: [0..4096)  ws_se ([2][BT])   [4096..8192) ws_tg ([2][BT])
// bytes 32768+: bf16 arrays: Xbf, Xrbf, Wbf, Wrbf (element offsets below)
#define WS_BF_BYTE  32768
#define XBF_OFF     0
#define XRBF_OFF    (BT * HDIM)                    // 2097152
#define WBF_OFF     (2 * BT * HDIM)                // 4194304
#define WRBF_OFF    (2 * BT * HDIM + VDIM * HDIM)  // 36962304
#define CVT_TOTAL   (2 * BT * HDIM + 2 * VDIM * HDIM)  // 69730304
#define WS_NEED     ((size_t)WS_BF_BYTE + (size_t)CVT_TOTAL * 2)

__device__ __forceinline__ unsigned short f2bf_rne(float f) {
  unsigned int u = __builtin_bit_cast(unsigned int, f);
  u += 0x7fffu + ((u >> 16) & 1u);
  return (unsigned short)(u >> 16);
}

__device__ __forceinline__ u16x8 cvt8(float4 a, float4 b) {
  u16x8 v;
  v[0] = f2bf_rne(a.x); v[1] = f2bf_rne(a.y); v[2] = f2bf_rne(a.z); v[3] = f2bf_rne(a.w);
  v[4] = f2bf_rne(b.x); v[5] = f2bf_rne(b.y); v[6] = f2bf_rne(b.z); v[7] = f2bf_rne(b.w);
  return v;
}

__global__ __launch_bounds__(256) void kto_zero_ws(float* p) {
  p[blockIdx.x * 256 + threadIdx.x] = 0.0f;
}

// fp32 -> bf16 one-shot conversion of X, Xr, W, Wr into ws. HBM-bound.
__global__ __launch_bounds__(256) void kto_convert(
    const float* __restrict__ X, const float* __restrict__ Xr,
    const float* __restrict__ W, const float* __restrict__ Wr,
    unsigned short* __restrict__ bf)
{
  size_t gid8 = ((size_t)blockIdx.x * 256 + threadIdx.x) * 8;
  if (gid8 >= (size_t)CVT_TOTAL) return;
  const float* src; size_t off;
  if (gid8 < (size_t)XRBF_OFF)      { src = X;  off = gid8; }
  else if (gid8 < (size_t)WBF_OFF)  { src = Xr; off = gid8 - XRBF_OFF; }
  else if (gid8 < (size_t)WRBF_OFF) { src = W;  off = gid8 - WBF_OFF; }
  else                              { src = Wr; off = gid8 - WRBF_OFF; }
  const float4* p = (const float4*)(src + off);
  float4 a = p[0], b = p[1];
  *(u16x8*)(bf + gid8) = cvt8(a, b);
}

#define GLD16(g, l) __builtin_amdgcn_global_load_lds( \
    (const __attribute__((address_space(1))) unsigned int*)(g), \
    (__attribute__((address_space(3))) unsigned int*)(l), 16, 0, 0)

// m97-structure fused GEMM + logsumexp partials. bf16 inputs from ws.
// grid = (BT/128, VDIM/128, 2 models), block = 256 (4 waves, 2x2 of 64x64)
__global__ __launch_bounds__(256) void kto_lse_gemm_fast(
    const unsigned short* __restrict__ bf,
    const float* __restrict__ Bp, const float* __restrict__ Br,
    const int* __restrict__ target,
    float* __restrict__ ws_se, float* __restrict__ ws_tg)
{
  const int model = blockIdx.z;
  const unsigned short* __restrict__ Xb = bf + (model ? XRBF_OFF : XBF_OFF);
  const unsigned short* __restrict__ Wb = bf + (model ? WRBF_OFF : WBF_OFF);
  const float* __restrict__ Bv = model ? Br : Bp;

  __shared__ unsigned short Asm[128 * 32];  // 8 KB, row = 64 B, NO pad (global_load_lds)
  __shared__ unsigned short Bsm[128 * 32];  // 8 KB

  const int tid  = threadIdx.x;
  const int wave = tid >> 6;
  const int lane = tid & 63;
  const int q    = lane >> 4;
  const int c    = lane & 15;
  const int mW   = (wave >> 1) * 64;
  const int nW   = (wave & 1) * 64;
  const int mBase = blockIdx.x * 128;
  const int nBase = blockIdx.y * 128;

  // staging: 16 segments of 1 KB (16 rows x 64 B); wave w issues segs 4w..4w+3.
  // LDS dest = wave-uniform base + lane*16. Lane covers row lrow, swizzled chunk.
  const int lrow = lane >> 2;                       // row within segment
  const int lchk = (lane & 3) ^ ((lane >> 3) & 3);  // XOR-swizzled 16B chunk

  const char* gsrc[4];
  unsigned short* ldst[4];
  #pragma unroll
  for (int j = 0; j < 4; ++j) {
    const int seg = wave * 4 + j;
    if (seg < 8) {
      const int row = mBase + seg * 16 + lrow;
      gsrc[j] = (const char*)Xb + (size_t)row * (HDIM * 2) + lchk * 16;
      ldst[j] = &Asm[seg * 512];
    } else {
      const int row = nBase + (seg - 8) * 16 + lrow;
      gsrc[j] = (const char*)Wb + (size_t)row * (HDIM * 2) + lchk * 16;
      ldst[j] = &Bsm[(seg - 8) * 512];
    }
  }

  // frag-read swizzle: chunk in LDS holding global chunk q at row ~c is q ^ ((c>>1)&3)
  const int swz = (q ^ ((c >> 1) & 3)) * 8;  // element offset within 32-elem row

  f32x4 acc[4][4] = {};

  for (int kt = 0; kt < HDIM / 32; ++kt) {
    __syncthreads();  // previous iter's frag reads complete before overwrite
    const size_t kb = (size_t)kt * 64;
    #pragma unroll
    for (int j = 0; j < 4; ++j)
      GLD16(gsrc[j] + kb, ldst[j]);
    __syncthreads();  // compiler emits vmcnt(0) drain before barrier

    bf16x8 afr[4], bfr[4];
    #pragma unroll
    for (int mi = 0; mi < 4; ++mi)
      afr[mi] = *(const bf16x8*)&Asm[(mW + mi * 16 + c) * 32 + swz];
    #pragma unroll
    for (int ni = 0; ni < 4; ++ni)
      bfr[ni] = *(const bf16x8*)&Bsm[(nW + ni * 16 + c) * 32 + swz];
    #pragma unroll
    for (int mi = 0; mi < 4; ++mi)
      #pragma unroll
      for (int ni = 0; ni < 4; ++ni)
        acc[mi][ni] = __builtin_amdgcn_mfma_f32_16x16x32_bf16(afr[mi], bfr[ni], acc[mi][ni], 0, 0, 0);
  }

  // epilogue: bias + exp + target pick, all in registers
  float se_acc[4][4] = {};
  float tg_acc[4][4] = {};
  int tgt_idx[4][4];
  #pragma unroll
  for (int mi = 0; mi < 4; ++mi)
    #pragma unroll
    for (int r = 0; r < 4; ++r)
      tgt_idx[mi][r] = target[mBase + mW + mi * 16 + q * 4 + r];

  #pragma unroll
  for (int ni = 0; ni < 4; ++ni) {
    const int col = nBase + nW + ni * 16 + c;
    const float bv = Bv[col];
    #pragma unroll
    for (int mi = 0; mi < 4; ++mi)
      #pragma unroll
      for (int r = 0; r < 4; ++r) {
        float logit = acc[mi][ni][r] + bv;
        se_acc[mi][r] += __expf(logit);
        if (tgt_idx[mi][r] == col) tg_acc[mi][r] += logit;
      }
  }

  // quad (16-lane) butterfly, then one atomic pair per row, spread across lanes
  #pragma unroll
  for (int mi = 0; mi < 4; ++mi)
    #pragma unroll
    for (int r = 0; r < 4; ++r) {
      float s = se_acc[mi][r];
      float t = tg_acc[mi][r];
      #pragma unroll
      for (int off = 1; off < 16; off <<= 1) {
        s += __shfl_xor(s, off, 64);
        t += __shfl_xor(t, off, 64);
      }
      if (c == ((mi << 2) | r)) {
        const int row = mBase + mW + mi * 16 + q * 4 + r;
        atomicAdd(&ws_se[model * BT + row], s);
        atomicAdd(&ws_tg[model * BT + row], t);
      }
    }
}

// ---------------- fallback (round-1, fp32-convert-in-loop) ----------------
#define SBM 128
#define SBN 128
#define SBK 32
#define SVSLICE 1280
#define SNITER  (SVSLICE / SBN)
#define SKTILES (HDIM / SBK)
#define SLDK    (SBK + 8)

__device__ __forceinline__ void cvt_store8s(unsigned short* dst, float4 a, float4 b) {
  *(u16x8*)dst = cvt8(a, b);
}

__global__ __launch_bounds__(256) void kto_lse_gemm_slow(
    const float* __restrict__ Xp, const float* __restrict__ Wp, const float* __restrict__ Bp,
    const float* __restrict__ Xr, const float* __restrict__ Wr, const float* __restrict__ Br,
    const int* __restrict__ target, float* __restrict__ ws_se, float* __restrict__ ws_tg)
{
  const int model = blockIdx.z;
  const float* __restrict__ X  = model ? Xr : Xp;
  const float* __restrict__ W  = model ? Wr : Wp;
  const float* __restrict__ Bv = model ? Br : Bp;

  __shared__ unsigned short Asm[SBM][SLDK];
  __shared__ unsigned short Bsm[SBN][SLDK];

  const int tid  = threadIdx.x;
  const int wave = tid >> 6;
  const int lane = tid & 63;
  const int q    = lane >> 4;
  const int c    = lane & 15;
  const int mW   = (wave >> 1) * 64;
  const int nW   = (wave & 1) * 64;
  const int mBase = blockIdx.x * SBM;
  const int vBase = blockIdx.y * SVSLICE;

  const int srow = tid >> 1;
  const int scol = (tid & 1) << 4;

  int tgt_idx[4][4];
  #pragma unroll
  for (int mi = 0; mi < 4; ++mi)
    #pragma unroll
    for (int r = 0; r < 4; ++r)
      tgt_idx[mi][r] = target[mBase + mW + mi * 16 + q * 4 + r];

  float se_acc[4][4] = {};
  float tg_acc[4][4] = {};

  for (int it = 0; it < SNITER; ++it) {
    const int nIterBase = vBase + it * SBN;
    f32x4 acc[4][4] = {};

    for (int kt = 0; kt < SKTILES; ++kt) {
      __syncthreads();
      {
        const float4* a4 = (const float4*)(X + (size_t)(mBase + srow) * HDIM + kt * SBK + scol);
        float4 a0 = a4[0], a1 = a4[1], a2 = a4[2], a3 = a4[3];
        const float4* b4 = (const float4*)(W + (size_t)(nIterBase + srow) * HDIM + kt * SBK + scol);
        float4 b0 = b4[0], b1 = b4[1], b2 = b4[2], b3 = b4[3];
        cvt_store8s(&Asm[srow][scol],     a0, a1);
        cvt_store8s(&Asm[srow][scol + 8], a2, a3);
        cvt_store8s(&Bsm[srow][scol],     b0, b1);
        cvt_store8s(&Bsm[srow][scol + 8], b2, b3);
      }
      __syncthreads();

      bf16x8 afr[4], bfr[4];
      #pragma unroll
      for (int mi = 0; mi < 4; ++mi)
        afr[mi] = *(const bf16x8*)&Asm[mW + mi * 16 + c][q * 8];
      #pragma unroll
      for (int ni = 0; ni < 4; ++ni)
        bfr[ni] = *(const bf16x8*)&Bsm[nW + ni * 16 + c][q * 8];
      #pragma unroll
      for (int mi = 0; mi < 4; ++mi)
        #pragma unroll
        for (int ni = 0; ni < 4; ++ni)
          acc[mi][ni] = __builtin_amdgcn_mfma_f32_16x16x32_bf16(afr[mi], bfr[ni], acc[mi][ni], 0, 0, 0);
    }

    #pragma unroll
    for (int ni = 0; ni < 4; ++ni) {
      const int col = nIterBase + nW + ni * 16 + c;
      const float bv = Bv[col];
      #pragma unroll
      for (int mi = 0; mi < 4; ++mi)
        #pragma unroll
        for (int r = 0; r < 4; ++r) {
          float logit = acc[mi][ni][r] + bv;
          se_acc[mi][r] += __expf(logit);
          if (tgt_idx[mi][r] == col) tg_acc[mi][r] += logit;
        }
    }
  }

  #pragma unroll
  for (int mi = 0; mi < 4; ++mi)
    #pragma unroll
    for (int r = 0; r < 4; ++r) {
      float s = se_acc[mi][r];
      float t = tg_acc[mi][r];
      #pragma unroll
      for (int off = 1; off < 16; off <<= 1) {
        s += __shfl_xor(s, off, 64);
        t += __shfl_xor(t, off, 64);
      }
      if (c == 0) {
        const int row = mBase + mW + mi * 16 + q * 4 + r;
        atomicAdd(&ws_se[model * BT + row], s);
        atomicAdd(&ws_tg[model * BT + row], t);
      }
    }
}

__global__ __launch_bounds__(256) void kto_finalize(
    const float* __restrict__ ws_se, const float* __restrict__ ws_tg,
    const int* __restrict__ target, const int* __restrict__ pref,
    const float* __restrict__ kl, float* __restrict__ out)
{
  __shared__ float lr[NSEQ];
  const int tid = threadIdx.x;
  if (tid < NSEQ) lr[tid] = 0.0f;
  __syncthreads();
  for (int t = tid; t < BT; t += 256) {
    float d = 0.0f;
    if (target[t] != IGNORE_IDX) {
      float lp_p = ws_tg[t]      - __logf(ws_se[t]);
      float lp_r = ws_tg[BT + t] - __logf(ws_se[BT + t]);
      d = lp_p - lp_r;
    }
    atomicAdd(&lr[t >> 9], d);
  }
  __syncthreads();
  if (tid == 0) {
    float loss = 0.f, ch = 0.f, rj = 0.f;
    const float klv = kl[0];
    for (int b = 0; b < NSEQ; ++b) {
      float logratio = lr[b];
      bool p = pref[b] != 0;
      float mult = p ? 1.0f : -1.0f;
      float z = BETA * (logratio - klv) * mult;
      float sig = 1.0f / (1.0f + __expf(-z));
      loss += 1.0f - sig;
      float rw = BETA * logratio;
      if (p) ch += rw; else rj += rw;
    }
    out[0] = loss / (float)BT;
    out[1] = ch;
    out[2] = rj;
  }
}

extern "C" void kernel_launch(void* const* d_in, const int* in_sizes, int n_in,
                              void* d_out, int out_size, void* d_ws, size_t ws_size,
                              hipStream_t stream) {
  (void)in_sizes; (void)n_in; (void)out_size;
  const float* X    = (const float*)d_in[0];
  const float* W    = (const float*)d_in[1];
  const int*   tgt  = (const int*)d_in[2];
  const float* bias = (const float*)d_in[3];
  const int*   pref = (const int*)d_in[4];
  const float* Xr   = (const float*)d_in[5];
  const float* Wr   = (const float*)d_in[6];
  const float* br   = (const float*)d_in[7];
  const float* kl   = (const float*)d_in[8];
  float* out = (float*)d_out;

  float* ws_se = (float*)d_ws;
  float* ws_tg = ws_se + 2 * BT;

  kto_zero_ws<<<32, 256, 0, stream>>>(ws_se);  // zero se+tg (8192 floats)

  if (ws_size >= WS_NEED) {
    unsigned short* bf = (unsigned short*)((char*)d_ws + WS_BF_BYTE);
    kto_convert<<<(CVT_TOTAL / 2048), 256, 0, stream>>>(X, Xr, W, Wr, bf);
    dim3 grid(BT / 128, VDIM / 128, 2);  // (16, 250, 2)
    kto_lse_gemm_fast<<<grid, 256, 0, stream>>>(bf, bias, br, tgt, ws_se, ws_tg);
  } else {
    dim3 grid(BT / SBM, VDIM / SVSLICE, 2);  // (16, 25, 2)
    kto_lse_gemm_slow<<<grid, 256, 0, stream>>>(X, W, bias, Xr, Wr, br, tgt, ws_se, ws_tg);
  }

  kto_finalize<<<1, 256, 0, stream>>>(ws_se, ws_tg, tgt, pref, kl, out);
}